// Round 1
// baseline (260.968 us; speedup 1.0000x reference)
//
#include <hip/hip_runtime.h>

#define D 4096
#define DM (D - 1)
#define BS 128   // bundle size
#define NROW 64  // B * nb = 4 * 16

// swizzled LDS read of one float4 "group" (breaks bank conflicts for
// lane-strided group access while keeping 16B contiguity)
__device__ __forceinline__ float4 ldswz(const float* bsh, int G) {
  int pg = G ^ ((G >> 3) & 7);
  return *(const float4*)(bsh + (pg << 2));
}

// ---------------- kernel 1: softmax over the 128 position weights ----------
__global__ __launch_bounds__(128) void softmax_k(const float* __restrict__ pw,
                                                 float* __restrict__ w) {
  const int t = threadIdx.x;
  float v = pw[t];
  float m = v;
#pragma unroll
  for (int o = 32; o > 0; o >>= 1) m = fmaxf(m, __shfl_xor(m, o));
  __shared__ float sm[2];
  if ((t & 63) == 0) sm[t >> 6] = m;
  __syncthreads();
  m = fmaxf(sm[0], sm[1]);
  float e = expf(v - m);
  float s = e;
#pragma unroll
  for (int o = 32; o > 0; o >>= 1) s += __shfl_xor(s, o);
  __shared__ float ss[2];
  if ((t & 63) == 0) ss[t >> 6] = s;
  __syncthreads();
  s = ss[0] + ss[1];
  w[t] = e / s;
}

// ---------------- kernel 2: z[row,m] = sum_s w[s] * tok[row,s,(m+s)%D] -----
// grid (16 s-chunks of 8, 64 rows); partials so no atomics needed.
__global__ __launch_bounds__(256) void shift_k(const float* __restrict__ tok,
                                               const float* __restrict__ w,
                                               float* __restrict__ part) {
  const int t = threadIdx.x;
  const int c = blockIdx.x;    // 0..15
  const int row = blockIdx.y;  // 0..63
  const float* tr = tok + (size_t)row * (BS * D);
  float acc[16];
#pragma unroll
  for (int i = 0; i < 16; ++i) acc[i] = 0.f;
#pragma unroll
  for (int s8 = 0; s8 < 8; ++s8) {
    const int s = (c << 3) + s8;
    const float wv = w[s];
    const float* tp = tr + (size_t)s * D;
#pragma unroll
    for (int i = 0; i < 16; ++i) {
      const int j = (t + (i << 8) + s) & DM;  // (m + s) mod D, coalesced per lane
      acc[i] += wv * tp[j];
    }
  }
  float* pz = part + (size_t)(c * NROW + row) * D;
#pragma unroll
  for (int i = 0; i < 16; ++i) pz[t + (i << 8)] = acc[i];
}

// ---------------- kernel 3: bundle[row,d] = sum_m z[m]*base[(m-d)%D] -------
// grid (4, 64): blockIdx.x = (jhalf<<1)|dchunk. Each block: 2048 j x 2048 d.
// 8 consecutive d per thread; sliding 12-float window of base in registers.
__global__ __launch_bounds__(256) void corr_k(const float* __restrict__ part,
                                              const float* __restrict__ base,
                                              float* __restrict__ braw) {
  __shared__ float zsh[2048];
  __shared__ float bsh[8192];
  const int t = threadIdx.x;
  const int dchunk = blockIdx.x & 1;
  const int jhalf = blockIdx.x >> 1;
  const int row = blockIdx.y;

  // stage z (sum of 16 partials) for this j-half
#pragma unroll
  for (int i = 0; i < 8; ++i) {
    const int ml = t + (i << 8);
    const int mg = (jhalf << 11) + ml;
    float s = 0.f;
#pragma unroll
    for (int cc = 0; cc < 16; ++cc)
      s += part[(size_t)(cc * NROW + row) * D + mg];
    zsh[ml] = s;
  }
  // stage base replicated 2x, XOR-swizzled by float4 group
  for (int l = t; l < 8192; l += 256) {
    const int g = l >> 2;
    const int pg = g ^ ((g >> 3) & 7);
    bsh[(pg << 2) | (l & 3)] = base[l & DM];
  }
  __syncthreads();

  const int d0 = (dchunk << 11) + (t << 3);  // 8 consecutive d per thread
  const int jb = jhalf << 11;
  const int G0 = (jb + D - d0) >> 2;  // >= 2 always
  float acc[8];
#pragma unroll
  for (int k = 0; k < 8; ++k) acc[k] = 0.f;

  float4 win[4];
  win[2] = ldswz(bsh, G0 - 2);
  win[3] = ldswz(bsh, G0 - 1);
#pragma unroll 4
  for (int i = 0; i < 512; ++i) {
    win[i & 3] = ldswz(bsh, G0 + i);                 // per-lane, 2-way max
    const float4 zv = *(const float4*)(zsh + (i << 2));  // broadcast
    const float4 A = win[(i + 2) & 3];
    const float4 Bv = win[(i + 3) & 3];
    const float4 Cv = win[i & 3];
    const float wf[12] = {A.x, A.y, A.z, A.w, Bv.x, Bv.y, Bv.z, Bv.w,
                          Cv.x, Cv.y, Cv.z, Cv.w};
    const float zz[4] = {zv.x, zv.y, zv.z, zv.w};
#pragma unroll
    for (int k = 0; k < 8; ++k) {
#pragma unroll
      for (int jj = 0; jj < 4; ++jj)
        acc[k] += zz[jj] * wf[8 + jj - k];  // base[(m - d) mod D]
    }
  }
  float* op = braw + (size_t)((jhalf << 6) + row) * D + d0;
#pragma unroll
  for (int k = 0; k < 8; ++k) op[k] = acc[k];
}

// ---------------- kernel 4: sum j-halves + L2 normalize --------------------
__global__ __launch_bounds__(256) void norm_k(const float* __restrict__ braw,
                                              float* __restrict__ out) {
  const int t = threadIdx.x;
  const int row = blockIdx.x;
  const float* r0 = braw + (size_t)row * D;
  const float* r1 = braw + (size_t)(NROW + row) * D;
  float v[16];
  float ssq = 0.f;
#pragma unroll
  for (int i = 0; i < 16; ++i) {
    const int m = t + (i << 8);
    const float x = r0[m] + r1[m];
    v[i] = x;
    ssq += x * x;
  }
#pragma unroll
  for (int o = 32; o > 0; o >>= 1) ssq += __shfl_xor(ssq, o);
  __shared__ float sw[4];
  if ((t & 63) == 0) sw[t >> 6] = ssq;
  __syncthreads();
  ssq = sw[0] + sw[1] + sw[2] + sw[3];
  const float sc = rsqrtf(fmaxf(ssq, 1e-8f));
  float* op = out + (size_t)row * D;
#pragma unroll
  for (int i = 0; i < 16; ++i) op[t + (i << 8)] = v[i] * sc;
}

extern "C" void kernel_launch(void* const* d_in, const int* in_sizes, int n_in,
                              void* d_out, int out_size, void* d_ws, size_t ws_size,
                              hipStream_t stream) {
  (void)in_sizes; (void)n_in; (void)out_size; (void)ws_size;
  const float* tok = (const float*)d_in[0];   // [4,2048,4096] f32
  const float* base = (const float*)d_in[1];  // [4096] f32
  const float* pw = (const float*)d_in[2];    // [128] f32
  float* out = (float*)d_out;                 // [64,4096] f32

  float* w = (float*)d_ws;                    // 128 floats (pad to 256)
  float* part = w + 256;                      // 16*64*4096 floats (16 MB)
  float* braw = part + (size_t)16 * NROW * D; // 2*64*4096 floats (2 MB)

  softmax_k<<<1, 128, 0, stream>>>(pw, w);
  shift_k<<<dim3(16, 64), 256, 0, stream>>>(tok, w, part);
  corr_k<<<dim3(4, 64), 256, 0, stream>>>(part, base, braw);
  norm_k<<<NROW, 256, 0, stream>>>(braw, out);
}

// Round 2
// 228.429 us; speedup vs baseline: 1.1424x; 1.1424x over previous
//
#include <hip/hip_runtime.h>

#define D 4096
#define DM (D - 1)
#define BS 128   // bundle size
#define NROW 64  // B * nb = 4 * 16
#define QC 8     // shift partial planes (q-chunks of 4 q = 16 s each)
#define JC 8     // corr partial planes (j-chunks of 512)

// swizzled LDS access of one float4 "group": pg = g ^ ((g>>3)&7) permutes
// within 64-group tiles; with per-lane group stride -4 this distributes
// 64 lanes uniformly over the 8 bank-sets (the b128 minimum).
__device__ __forceinline__ float4 ldswz(const float* bsh, int G) {
  const int pg = G ^ ((G >> 3) & 7);
  return *(const float4*)(bsh + (pg << 2));
}

// ---------- kernel 1: z partials, softmax folded in ------------------------
// part[qc][row][m] = sum_{s in 16-chunk} softmax(pw)[s] * tok[row][s][(m+s)%D]
__global__ __launch_bounds__(256) void shift_k(const float* __restrict__ tok,
                                               const float* __restrict__ pw,
                                               float* __restrict__ part) {
  const int t = threadIdx.x;
  const int qc = blockIdx.x;   // 0..7
  const int row = blockIdx.y;  // 0..63

  // --- inline softmax over 128 weights -> wsh ---
  __shared__ float wsh[BS];
  __shared__ float red[4];
  {
    const float v = (t < BS) ? pw[t] : -1e30f;
    float m = v;
#pragma unroll
    for (int o = 32; o > 0; o >>= 1) m = fmaxf(m, __shfl_xor(m, o));
    if ((t & 63) == 0) red[t >> 6] = m;
    __syncthreads();
    m = fmaxf(fmaxf(red[0], red[1]), fmaxf(red[2], red[3]));
    const float e = (t < BS) ? expf(v - m) : 0.f;
    float s = e;
#pragma unroll
    for (int o = 32; o > 0; o >>= 1) s += __shfl_xor(s, o);
    __syncthreads();
    if ((t & 63) == 0) red[t >> 6] = s;
    __syncthreads();
    s = red[0] + red[1] + red[2] + red[3];
    if (t < BS) wsh[t] = e / s;
    __syncthreads();
  }
  // hoist this block's 16 weights into registers
  float wv[16];
#pragma unroll
  for (int j = 0; j < 16; ++j) wv[j] = wsh[(qc << 4) + j];

  const float4* tr = (const float4*)(tok + (size_t)row * (BS * D));
  float4 acc[4];
#pragma unroll
  for (int g = 0; g < 4; ++g) acc[g] = make_float4(0.f, 0.f, 0.f, 0.f);

#pragma unroll
  for (int qq = 0; qq < 4; ++qq) {
    const int q = (qc << 2) + qq;
    const float w0 = wv[4 * qq + 0], w1 = wv[4 * qq + 1];
    const float w2 = wv[4 * qq + 2], w3 = wv[4 * qq + 3];
#pragma unroll
    for (int g = 0; g < 4; ++g) {
      const int G = (t + (g << 8) + q) & 1023;   // float4-group of (m+s)
      const int G1 = (G + 1) & 1023;
      const size_t r0 = (size_t)(4 * q + 0) << 10;
      const size_t r1 = (size_t)(4 * q + 1) << 10;
      const size_t r2 = (size_t)(4 * q + 2) << 10;
      const size_t r3 = (size_t)(4 * q + 3) << 10;
      const float4 a0 = tr[r0 + G];
      const float4 a1 = tr[r1 + G], b1 = tr[r1 + G1];
      const float4 a2 = tr[r2 + G], b2 = tr[r2 + G1];
      const float4 a3 = tr[r3 + G], b3 = tr[r3 + G1];
      // r=0: element k
      acc[g].x += w0 * a0.x; acc[g].y += w0 * a0.y;
      acc[g].z += w0 * a0.z; acc[g].w += w0 * a0.w;
      // r=1: element k+1 (spills into next group at k=3)
      acc[g].x += w1 * a1.y; acc[g].y += w1 * a1.z;
      acc[g].z += w1 * a1.w; acc[g].w += w1 * b1.x;
      // r=2
      acc[g].x += w2 * a2.z; acc[g].y += w2 * a2.w;
      acc[g].z += w2 * b2.x; acc[g].w += w2 * b2.y;
      // r=3
      acc[g].x += w3 * a3.w; acc[g].y += w3 * b3.x;
      acc[g].z += w3 * b3.y; acc[g].w += w3 * b3.z;
    }
  }
  float4* pz = (float4*)(part + (size_t)(qc * NROW + row) * D);
#pragma unroll
  for (int g = 0; g < 4; ++g) pz[t + (g << 8)] = acc[g];
}

// ---------- kernel 2: bundle partials ---------------------------------------
// braw[jc][row][d] = sum_{m in 512-chunk} z[row][m] * base[(m-d)%D]
__global__ __launch_bounds__(256) void corr_k(const float* __restrict__ part,
                                              const float* __restrict__ base,
                                              float* __restrict__ braw) {
  __shared__ __align__(16) float zsh[512];
  __shared__ __align__(16) float bsh[4608];
  const int t = threadIdx.x;
  const int jc = blockIdx.x;   // 0..7
  const int row = blockIdx.y;  // 0..63
  const int jb = jc << 9;

  // stage z chunk: sum the 8 shift partials
#pragma unroll
  for (int i = 0; i < 2; ++i) {
    const int ml = t + (i << 8);
    const int mg = jb + ml;
    float s = 0.f;
#pragma unroll
    for (int cc = 0; cc < QC; ++cc)
      s += part[(size_t)(cc * NROW + row) * D + mg];
    zsh[ml] = s;
  }
  // stage base window: bsh[x] <-> base[(x + jb) & DM], x in [0,4608), swizzled
  for (int x = t; x < 4608; x += 256) {
    const int g = x >> 2;
    const int pg = g ^ ((g >> 3) & 7);
    bsh[(pg << 2) | (x & 3)] = base[(x + jb) & DM];
  }
  __syncthreads();

  // thread owns d = 16t .. 16t+15; float index of base[(m-d)%D] within bsh:
  // x = 4*Gtop + (jj - k), Gtop = Gb + i, Gb = 1024 - 4t
  const int Gb = 1024 - 4 * t;
  float acc[16];
#pragma unroll
  for (int k = 0; k < 16; ++k) acc[k] = 0.f;

  float4 win[8];
  win[4] = ldswz(bsh, Gb - 4);
  win[5] = ldswz(bsh, Gb - 3);
  win[6] = ldswz(bsh, Gb - 2);
  win[7] = ldswz(bsh, Gb - 1);

  const float4* zsh4 = (const float4*)zsh;
  for (int io = 0; io < 16; ++io) {
#pragma unroll
    for (int ic = 0; ic < 8; ++ic) {
      const int i = (io << 3) + ic;          // i & 7 == ic (compile-time)
      win[ic] = ldswz(bsh, Gb + i);          // group Gtop(i)
      const float4 zv = zsh4[i];             // broadcast
      const float4 u0 = win[(ic + 4) & 7];   // group Gtop-4
      const float4 u1 = win[(ic + 5) & 7];
      const float4 u2 = win[(ic + 6) & 7];
      const float4 u3 = win[(ic + 7) & 7];
      const float4 u4 = win[ic];             // group Gtop
      const float wf[20] = {u0.x, u0.y, u0.z, u0.w, u1.x, u1.y, u1.z, u1.w,
                            u2.x, u2.y, u2.z, u2.w, u3.x, u3.y, u3.z, u3.w,
                            u4.x, u4.y, u4.z, u4.w};
      const float zz[4] = {zv.x, zv.y, zv.z, zv.w};
#pragma unroll
      for (int k = 0; k < 16; ++k) {
#pragma unroll
        for (int jj = 0; jj < 4; ++jj)
          acc[k] += zz[jj] * wf[16 + jj - k];
      }
    }
  }
  float4* op4 = (float4*)(braw + (size_t)(jc * NROW + row) * D + (t << 4));
  op4[0] = make_float4(acc[0], acc[1], acc[2], acc[3]);
  op4[1] = make_float4(acc[4], acc[5], acc[6], acc[7]);
  op4[2] = make_float4(acc[8], acc[9], acc[10], acc[11]);
  op4[3] = make_float4(acc[12], acc[13], acc[14], acc[15]);
}

// ---------- kernel 3: sum j-partials + L2 normalize -------------------------
__global__ __launch_bounds__(1024) void norm_k(const float* __restrict__ braw,
                                               float* __restrict__ out) {
  const int t = threadIdx.x;   // 0..1023 (one float4 group each)
  const int row = blockIdx.x;
  const float4* b4 = (const float4*)braw;
  float4 s = make_float4(0.f, 0.f, 0.f, 0.f);
#pragma unroll
  for (int p = 0; p < JC; ++p) {
    const float4 v = b4[(size_t)(p * NROW + row) * (D / 4) + t];
    s.x += v.x; s.y += v.y; s.z += v.z; s.w += v.w;
  }
  float ssq = s.x * s.x + s.y * s.y + s.z * s.z + s.w * s.w;
#pragma unroll
  for (int o = 32; o > 0; o >>= 1) ssq += __shfl_xor(ssq, o);
  __shared__ float red[16];
  if ((t & 63) == 0) red[t >> 6] = ssq;
  __syncthreads();
  float tot = 0.f;
#pragma unroll
  for (int i = 0; i < 16; ++i) tot += red[i];
  const float sc = rsqrtf(fmaxf(tot, 1e-8f));
  float4 o;
  o.x = s.x * sc; o.y = s.y * sc; o.z = s.z * sc; o.w = s.w * sc;
  ((float4*)out)[(size_t)row * (D / 4) + t] = o;
}

extern "C" void kernel_launch(void* const* d_in, const int* in_sizes, int n_in,
                              void* d_out, int out_size, void* d_ws, size_t ws_size,
                              hipStream_t stream) {
  (void)in_sizes; (void)n_in; (void)out_size; (void)ws_size;
  const float* tok = (const float*)d_in[0];   // [4,2048,4096] f32
  const float* base = (const float*)d_in[1];  // [4096] f32
  const float* pw = (const float*)d_in[2];    // [128] f32
  float* out = (float*)d_out;                 // [64,4096] f32

  float* part = (float*)d_ws;                        // QC*64*4096 f32 (8 MB)
  float* braw = part + (size_t)QC * NROW * D;        // JC*64*4096 f32 (8 MB)

  shift_k<<<dim3(QC, NROW), 256, 0, stream>>>(tok, pw, part);
  corr_k<<<dim3(JC, NROW), 256, 0, stream>>>(part, base, braw);
  norm_k<<<NROW, 1024, 0, stream>>>(braw, out);
}

// Round 4
// 208.524 us; speedup vs baseline: 1.2515x; 1.0955x over previous
//
#include <hip/hip_runtime.h>

#define D 4096
#define DM 4095
#define BS 128   // bundle size
#define NROW 64  // B * nb = 4 * 16
#define QC 8     // shift partial planes
#define JC 8     // corr K-chunks (512 m each)

#define ZSTR 520  // u16 stride of zsh rows (65 groups, ==1 mod 8 -> conflict-free)
#define PSTR 616  // u16 stride of parity rows (77 groups, ==5 mod 8)

typedef __attribute__((ext_vector_type(8))) short bf16x8;
typedef __attribute__((ext_vector_type(4))) float f32x4;

// round-to-nearest-even f32 -> bf16 bits
__device__ __forceinline__ unsigned short f2bf(float f) {
  union { float f; unsigned int u; } v;
  v.f = f;
  const unsigned int r = v.u + 0x7fffu + ((v.u >> 16) & 1u);
  return (unsigned short)(r >> 16);
}

// ---------- kernel 1: z partials, softmax folded in ------------------------
// part[qc][row][m] = sum_{s in 16-chunk} softmax(pw)[s] * tok[row][s][(m+s)%D]
__global__ __launch_bounds__(256) void shift_k(const float* __restrict__ tok,
                                               const float* __restrict__ pw,
                                               float* __restrict__ part) {
  const int t = threadIdx.x;
  const int qc = blockIdx.x;   // 0..7
  const int row = blockIdx.y;  // 0..63

  __shared__ float wsh[BS];
  __shared__ float red[4];
  {
    const float v = (t < BS) ? pw[t] : -1e30f;
    float m = v;
#pragma unroll
    for (int o = 32; o > 0; o >>= 1) m = fmaxf(m, __shfl_xor(m, o));
    if ((t & 63) == 0) red[t >> 6] = m;
    __syncthreads();
    m = fmaxf(fmaxf(red[0], red[1]), fmaxf(red[2], red[3]));
    const float e = (t < BS) ? expf(v - m) : 0.f;
    float s = e;
#pragma unroll
    for (int o = 32; o > 0; o >>= 1) s += __shfl_xor(s, o);
    __syncthreads();
    if ((t & 63) == 0) red[t >> 6] = s;
    __syncthreads();
    s = red[0] + red[1] + red[2] + red[3];
    if (t < BS) wsh[t] = e / s;
    __syncthreads();
  }
  float wv[16];
#pragma unroll
  for (int j = 0; j < 16; ++j) wv[j] = wsh[(qc << 4) + j];

  const float4* tr = (const float4*)(tok + (size_t)row * (BS * D));
  float4 acc[4];
#pragma unroll
  for (int g = 0; g < 4; ++g) acc[g] = make_float4(0.f, 0.f, 0.f, 0.f);

#pragma unroll
  for (int qq = 0; qq < 4; ++qq) {
    const int q = (qc << 2) + qq;
    const float w0 = wv[4 * qq + 0], w1 = wv[4 * qq + 1];
    const float w2 = wv[4 * qq + 2], w3 = wv[4 * qq + 3];
#pragma unroll
    for (int g = 0; g < 4; ++g) {
      const int G = (t + (g << 8) + q) & 1023;
      const int G1 = (G + 1) & 1023;
      const size_t r0 = (size_t)(4 * q + 0) << 10;
      const size_t r1 = (size_t)(4 * q + 1) << 10;
      const size_t r2 = (size_t)(4 * q + 2) << 10;
      const size_t r3 = (size_t)(4 * q + 3) << 10;
      const float4 a0 = tr[r0 + G];
      const float4 a1 = tr[r1 + G], b1 = tr[r1 + G1];
      const float4 a2 = tr[r2 + G], b2 = tr[r2 + G1];
      const float4 a3 = tr[r3 + G], b3 = tr[r3 + G1];
      acc[g].x += w0 * a0.x; acc[g].y += w0 * a0.y;
      acc[g].z += w0 * a0.z; acc[g].w += w0 * a0.w;
      acc[g].x += w1 * a1.y; acc[g].y += w1 * a1.z;
      acc[g].z += w1 * a1.w; acc[g].w += w1 * b1.x;
      acc[g].x += w2 * a2.z; acc[g].y += w2 * a2.w;
      acc[g].z += w2 * b2.x; acc[g].w += w2 * b2.y;
      acc[g].x += w3 * a3.w; acc[g].y += w3 * b3.x;
      acc[g].z += w3 * b3.y; acc[g].w += w3 * b3.z;
    }
  }
  float4* pz = (float4*)(part + (size_t)(qc * NROW + row) * D);
#pragma unroll
  for (int g = 0; g < 4; ++g) pz[t + (g << 8)] = acc[g];
}

// ---------- kernel 2: collapse partials -> z (bf16) -------------------------
__global__ __launch_bounds__(256) void z_k(const float* __restrict__ part,
                                           unsigned short* __restrict__ zb) {
  const int t = threadIdx.x;
  const int mq = blockIdx.x;   // 0..3
  const int row = blockIdx.y;  // 0..63
  const int m0 = (mq << 10) + (t << 2);
  float4 s = make_float4(0.f, 0.f, 0.f, 0.f);
#pragma unroll
  for (int cc = 0; cc < QC; ++cc) {
    const float4 v = *(const float4*)(part + (size_t)(cc * NROW + row) * D + m0);
    s.x += v.x; s.y += v.y; s.z += v.z; s.w += v.w;
  }
  ushort4 o;
  o.x = f2bf(s.x); o.y = f2bf(s.y); o.z = f2bf(s.z); o.w = f2bf(s.w);
  *(ushort4*)(zb + (size_t)row * D + m0) = o;
}

// ---------- kernel 3: circulant matmul via bf16 MFMA ------------------------
// braw[jc][row][d] = sum_{m in chunk} z[row][m] * base[(m-d)%D]
// C^T formulation: M=d (A = circulant), N=row (B = z), K=m.
__global__ __launch_bounds__(256) void corr_k(const unsigned short* __restrict__ zb,
                                              const float* __restrict__ base,
                                              float* __restrict__ braw) {
  __shared__ __align__(16) unsigned short zsh[16 * ZSTR];  // 16 rows x 512 bf16
  __shared__ __align__(16) unsigned short psh[8 * PSTR];   // 8 parity copies
  const int t = threadIdx.x;
  const int jc = blockIdx.x;   // 0..7   K-chunk
  const int dg = blockIdx.y;   // 0..63  64 d's per block
  const int rt = blockIdx.z;   // 0..3   16 rows per block
  const int jb = jc << 9;
  const int d0b = dg << 6;

  // stage zsh: 16 rows x 512 bf16; thread (rr = t>>4) writes 32 u16 at (t&15)*32
  {
    const int rr = t >> 4;
    const int c0 = (t & 15) << 5;
    const uint4* src =
        (const uint4*)(zb + (size_t)(rt * 16 + rr) * D + jb + c0);
    uint4* dst = (uint4*)(zsh + rr * ZSTR + c0);
    dst[0] = src[0];
    dst[1] = src[1];
    dst[2] = src[2];
    dst[3] = src[3];
  }
  // stage parity copies: psh[r][x] = bf16(base[(jb - d0b - 64 + r + x) & DM])
  {
    const int c0 = jb - d0b - 64 + 2 * D;  // keep positive
    for (int idx = t; idx < 8 * PSTR; idx += 256) {
      const int r = idx / PSTR;
      const int x = idx - r * PSTR;
      psh[idx] = f2bf(base[(c0 + r + x) & DM]);
    }
  }
  __syncthreads();

  const int lane = t & 63;
  const int w = t >> 6;        // wave id: d-subtile
  const int dd = lane & 15;    // A: m-index (d offset); B: n-index (row offset)
  const int q = lane >> 4;     // k = 8q + j
  // A fragment window start: a0 = 64 + 8q - 16w - dd (>=1), +32 per ks
  const int a0 = 64 + (q << 3) - (w << 4) - dd;
  const int pr = a0 & 7;
  const int px = a0 - pr;      // multiple of 8 -> 16B aligned
  const unsigned short* pA = psh + pr * PSTR + px;
  const unsigned short* pB = zsh + dd * ZSTR + (q << 3);

  f32x4 acc = {0.f, 0.f, 0.f, 0.f};
#pragma unroll
  for (int ks = 0; ks < 16; ++ks) {
    const bf16x8 af = *(const bf16x8*)(pA + (ks << 5));
    const bf16x8 bf = *(const bf16x8*)(pB + (ks << 5));
    acc = __builtin_amdgcn_mfma_f32_16x16x32_bf16(af, bf, acc, 0, 0, 0);
  }
  // D: col(n)=lane&15 -> output row; row(m)=quad*4+reg -> d index
  const int row = rt * 16 + dd;
  const int d = d0b + (w << 4) + (q << 2);
  float4 o = make_float4(acc[0], acc[1], acc[2], acc[3]);
  *(float4*)(braw + (size_t)(jc * NROW + row) * D + d) = o;
}

// ---------- kernel 4: sum K-chunk partials + L2 normalize -------------------
__global__ __launch_bounds__(1024) void norm_k(const float* __restrict__ braw,
                                               float* __restrict__ out) {
  const int t = threadIdx.x;
  const int row = blockIdx.x;
  const float4* b4 = (const float4*)braw;
  float4 s = make_float4(0.f, 0.f, 0.f, 0.f);
#pragma unroll
  for (int p = 0; p < JC; ++p) {
    const float4 v = b4[(size_t)(p * NROW + row) * (D / 4) + t];
    s.x += v.x; s.y += v.y; s.z += v.z; s.w += v.w;
  }
  float ssq = s.x * s.x + s.y * s.y + s.z * s.z + s.w * s.w;
#pragma unroll
  for (int o = 32; o > 0; o >>= 1) ssq += __shfl_xor(ssq, o);
  __shared__ float red[16];
  if ((t & 63) == 0) red[t >> 6] = ssq;
  __syncthreads();
  float tot = 0.f;
#pragma unroll
  for (int i = 0; i < 16; ++i) tot += red[i];
  const float sc = rsqrtf(fmaxf(tot, 1e-8f));
  float4 o;
  o.x = s.x * sc; o.y = s.y * sc; o.z = s.z * sc; o.w = s.w * sc;
  ((float4*)out)[(size_t)row * (D / 4) + t] = o;
}

extern "C" void kernel_launch(void* const* d_in, const int* in_sizes, int n_in,
                              void* d_out, int out_size, void* d_ws, size_t ws_size,
                              hipStream_t stream) {
  (void)in_sizes; (void)n_in; (void)out_size; (void)ws_size;
  const float* tok = (const float*)d_in[0];   // [4,2048,4096] f32
  const float* base = (const float*)d_in[1];  // [4096] f32
  const float* pw = (const float*)d_in[2];    // [128] f32
  float* out = (float*)d_out;                 // [64,4096] f32

  float* part = (float*)d_ws;                          // QC*64*4096 f32 (8 MB)
  float* braw = part + (size_t)QC * NROW * D;          // JC*64*4096 f32 (8 MB)
  unsigned short* zb =
      (unsigned short*)(braw + (size_t)JC * NROW * D); // 64*4096 bf16 (512 KB)

  shift_k<<<dim3(QC, NROW), 256, 0, stream>>>(tok, pw, part);
  z_k<<<dim3(4, NROW), 256, 0, stream>>>(part, zb);
  corr_k<<<dim3(JC, 64, 4), 256, 0, stream>>>(zb, base, braw);
  norm_k<<<NROW, 1024, 0, stream>>>(braw, out);
}

// Round 5
// 208.484 us; speedup vs baseline: 1.2517x; 1.0002x over previous
//
#include <hip/hip_runtime.h>

#define D 4096
#define DM 4095
#define BS 128   // bundle size
#define NROW 64  // B * nb = 4 * 16
#define QC 16    // shift partial planes (8 s each) -> 1024 blocks, 16 waves/CU
#define JC 8     // corr K-chunks (512 m each)

#define ZSTR 520  // u16 stride of zsh rows (65 groups, ==1 mod 8 -> conflict-free)
#define PSTR 616  // u16 stride of parity rows (77 groups, ==5 mod 8)

typedef __attribute__((ext_vector_type(8))) short bf16x8;
typedef __attribute__((ext_vector_type(4))) float f32x4;

// round-to-nearest-even f32 -> bf16 bits
__device__ __forceinline__ unsigned short f2bf(float f) {
  union { float f; unsigned int u; } v;
  v.f = f;
  const unsigned int r = v.u + 0x7fffu + ((v.u >> 16) & 1u);
  return (unsigned short)(r >> 16);
}

// ---------- kernel 1: z partials, softmax folded in ------------------------
// part[qc][row][m] = sum_{s in 8-chunk} softmax(pw)[s] * tok[row][s][(m+s)%D]
__global__ __launch_bounds__(256) void shift_k(const float* __restrict__ tok,
                                               const float* __restrict__ pw,
                                               float* __restrict__ part) {
  const int t = threadIdx.x;
  const int qc = blockIdx.x;   // 0..15
  const int row = blockIdx.y;  // 0..63

  __shared__ float wsh[BS];
  __shared__ float red[4];
  {
    const float v = (t < BS) ? pw[t] : -1e30f;
    float m = v;
#pragma unroll
    for (int o = 32; o > 0; o >>= 1) m = fmaxf(m, __shfl_xor(m, o));
    if ((t & 63) == 0) red[t >> 6] = m;
    __syncthreads();
    m = fmaxf(fmaxf(red[0], red[1]), fmaxf(red[2], red[3]));
    const float e = (t < BS) ? expf(v - m) : 0.f;
    float s = e;
#pragma unroll
    for (int o = 32; o > 0; o >>= 1) s += __shfl_xor(s, o);
    __syncthreads();
    if ((t & 63) == 0) red[t >> 6] = s;
    __syncthreads();
    s = red[0] + red[1] + red[2] + red[3];
    if (t < BS) wsh[t] = e / s;
    __syncthreads();
  }
  float wv[8];
#pragma unroll
  for (int j = 0; j < 8; ++j) wv[j] = wsh[(qc << 3) + j];

  const float4* tr = (const float4*)(tok + (size_t)row * (BS * D));
  float4 acc[4];
#pragma unroll
  for (int g = 0; g < 4; ++g) acc[g] = make_float4(0.f, 0.f, 0.f, 0.f);

#pragma unroll
  for (int qq = 0; qq < 2; ++qq) {
    const int q = (qc << 1) + qq;   // global s-quad index, s = 4q + r
    const float w0 = wv[4 * qq + 0], w1 = wv[4 * qq + 1];
    const float w2 = wv[4 * qq + 2], w3 = wv[4 * qq + 3];
#pragma unroll
    for (int g = 0; g < 4; ++g) {
      const int G = (t + (g << 8) + q) & 1023;
      const int G1 = (G + 1) & 1023;
      const size_t r0 = (size_t)(4 * q + 0) << 10;
      const size_t r1 = (size_t)(4 * q + 1) << 10;
      const size_t r2 = (size_t)(4 * q + 2) << 10;
      const size_t r3 = (size_t)(4 * q + 3) << 10;
      const float4 a0 = tr[r0 + G];
      const float4 a1 = tr[r1 + G], b1 = tr[r1 + G1];
      const float4 a2 = tr[r2 + G], b2 = tr[r2 + G1];
      const float4 a3 = tr[r3 + G], b3 = tr[r3 + G1];
      acc[g].x += w0 * a0.x; acc[g].y += w0 * a0.y;
      acc[g].z += w0 * a0.z; acc[g].w += w0 * a0.w;
      acc[g].x += w1 * a1.y; acc[g].y += w1 * a1.z;
      acc[g].z += w1 * a1.w; acc[g].w += w1 * b1.x;
      acc[g].x += w2 * a2.z; acc[g].y += w2 * a2.w;
      acc[g].z += w2 * b2.x; acc[g].w += w2 * b2.y;
      acc[g].x += w3 * a3.w; acc[g].y += w3 * b3.x;
      acc[g].z += w3 * b3.y; acc[g].w += w3 * b3.z;
    }
  }
  float4* pz = (float4*)(part + (size_t)(qc * NROW + row) * D);
#pragma unroll
  for (int g = 0; g < 4; ++g) pz[t + (g << 8)] = acc[g];
}

// ---------- kernel 2: collapse partials -> z (bf16) -------------------------
__global__ __launch_bounds__(256) void z_k(const float* __restrict__ part,
                                           unsigned short* __restrict__ zb) {
  const int t = threadIdx.x;
  const int mq = blockIdx.x;   // 0..3
  const int row = blockIdx.y;  // 0..63
  const int m0 = (mq << 10) + (t << 2);
  float4 s = make_float4(0.f, 0.f, 0.f, 0.f);
#pragma unroll
  for (int cc = 0; cc < QC; ++cc) {
    const float4 v = *(const float4*)(part + (size_t)(cc * NROW + row) * D + m0);
    s.x += v.x; s.y += v.y; s.z += v.z; s.w += v.w;
  }
  ushort4 o;
  o.x = f2bf(s.x); o.y = f2bf(s.y); o.z = f2bf(s.z); o.w = f2bf(s.w);
  *(ushort4*)(zb + (size_t)row * D + m0) = o;
}

// ---------- kernel 3: circulant matmul via bf16 MFMA ------------------------
// braw[jc][row][d] = sum_{m in chunk} z[row][m] * base[(m-d)%D]
// C^T formulation: M=d (A = circulant), N=row (B = z), K=m.
__global__ __launch_bounds__(256) void corr_k(const unsigned short* __restrict__ zb,
                                              const float* __restrict__ base,
                                              float* __restrict__ braw) {
  __shared__ __align__(16) unsigned short zsh[16 * ZSTR];  // 16 rows x 512 bf16
  __shared__ __align__(16) unsigned short psh[8 * PSTR];   // 8 parity copies
  const int t = threadIdx.x;
  const int jc = blockIdx.x;   // 0..7   K-chunk
  const int dg = blockIdx.y;   // 0..63  64 d's per block
  const int rt = blockIdx.z;   // 0..3   16 rows per block
  const int jb = jc << 9;
  const int d0b = dg << 6;

  // stage zsh: 16 rows x 512 bf16; thread (rr = t>>4) writes 32 u16 at (t&15)*32
  {
    const int rr = t >> 4;
    const int c0 = (t & 15) << 5;
    const uint4* src =
        (const uint4*)(zb + (size_t)(rt * 16 + rr) * D + jb + c0);
    uint4* dst = (uint4*)(zsh + rr * ZSTR + c0);
    dst[0] = src[0];
    dst[1] = src[1];
    dst[2] = src[2];
    dst[3] = src[3];
  }
  // stage parity copies: psh[r][x] = bf16(base[(jb - d0b - 64 + r + x) & DM])
  {
    const int c0 = jb - d0b - 64 + 2 * D;  // keep positive
    for (int idx = t; idx < 8 * PSTR; idx += 256) {
      const int r = idx / PSTR;
      const int x = idx - r * PSTR;
      psh[idx] = f2bf(base[(c0 + r + x) & DM]);
    }
  }
  __syncthreads();

  const int lane = t & 63;
  const int w = t >> 6;        // wave id: d-subtile
  const int dd = lane & 15;    // A: m-index (d offset); B: n-index (row offset)
  const int q = lane >> 4;     // k = 8q + j
  // A fragment window start: a0 = 64 + 8q - 16w - dd (>=1), +32 per ks
  const int a0 = 64 + (q << 3) - (w << 4) - dd;
  const int pr = a0 & 7;
  const int px = a0 - pr;      // multiple of 8 -> 16B aligned
  const unsigned short* pA = psh + pr * PSTR + px;
  const unsigned short* pB = zsh + dd * ZSTR + (q << 3);

  f32x4 acc = {0.f, 0.f, 0.f, 0.f};
#pragma unroll
  for (int ks = 0; ks < 16; ++ks) {
    const bf16x8 af = *(const bf16x8*)(pA + (ks << 5));
    const bf16x8 bf = *(const bf16x8*)(pB + (ks << 5));
    acc = __builtin_amdgcn_mfma_f32_16x16x32_bf16(af, bf, acc, 0, 0, 0);
  }
  // D: col(n)=lane&15 -> output row; row(m)=quad*4+reg -> d index
  const int row = rt * 16 + dd;
  const int d = d0b + (w << 4) + (q << 2);
  float4 o = make_float4(acc[0], acc[1], acc[2], acc[3]);
  *(float4*)(braw + (size_t)(jc * NROW + row) * D + d) = o;
}

// ---------- kernel 4: sum K-chunk partials + L2 normalize -------------------
__global__ __launch_bounds__(1024) void norm_k(const float* __restrict__ braw,
                                               float* __restrict__ out) {
  const int t = threadIdx.x;
  const int row = blockIdx.x;
  const float4* b4 = (const float4*)braw;
  float4 s = make_float4(0.f, 0.f, 0.f, 0.f);
#pragma unroll
  for (int p = 0; p < JC; ++p) {
    const float4 v = b4[(size_t)(p * NROW + row) * (D / 4) + t];
    s.x += v.x; s.y += v.y; s.z += v.z; s.w += v.w;
  }
  float ssq = s.x * s.x + s.y * s.y + s.z * s.z + s.w * s.w;
#pragma unroll
  for (int o = 32; o > 0; o >>= 1) ssq += __shfl_xor(ssq, o);
  __shared__ float red[16];
  if ((t & 63) == 0) red[t >> 6] = ssq;
  __syncthreads();
  float tot = 0.f;
#pragma unroll
  for (int i = 0; i < 16; ++i) tot += red[i];
  const float sc = rsqrtf(fmaxf(tot, 1e-8f));
  float4 o;
  o.x = s.x * sc; o.y = s.y * sc; o.z = s.z * sc; o.w = s.w * sc;
  ((float4*)out)[(size_t)row * (D / 4) + t] = o;
}

extern "C" void kernel_launch(void* const* d_in, const int* in_sizes, int n_in,
                              void* d_out, int out_size, void* d_ws, size_t ws_size,
                              hipStream_t stream) {
  (void)in_sizes; (void)n_in; (void)out_size; (void)ws_size;
  const float* tok = (const float*)d_in[0];   // [4,2048,4096] f32
  const float* base = (const float*)d_in[1];  // [4096] f32
  const float* pw = (const float*)d_in[2];    // [128] f32
  float* out = (float*)d_out;                 // [64,4096] f32

  float* part = (float*)d_ws;                          // QC*64*4096 f32 (16 MB)
  float* braw = part + (size_t)QC * NROW * D;          // JC*64*4096 f32 (8 MB)
  unsigned short* zb =
      (unsigned short*)(braw + (size_t)JC * NROW * D); // 64*4096 bf16 (512 KB)

  shift_k<<<dim3(QC, NROW), 256, 0, stream>>>(tok, pw, part);
  z_k<<<dim3(4, NROW), 256, 0, stream>>>(part, zb);
  corr_k<<<dim3(JC, 64, 4), 256, 0, stream>>>(zb, base, braw);
  norm_k<<<NROW, 1024, 0, stream>>>(braw, out);
}

// Round 6
// 205.774 us; speedup vs baseline: 1.2682x; 1.0132x over previous
//
#include <hip/hip_runtime.h>

#define D 4096
#define DM 4095
#define BS 128   // bundle size
#define NROW 64  // B * nb = 4 * 16
#define JC 8     // corr K-chunks (512 m each)

#define ZSTR 520  // u16 stride of zsh rows (65 groups, ==1 mod 8 -> conflict-free)
#define PSTR 616  // u16 stride of parity rows (77 groups, ==5 mod 8)

typedef __attribute__((ext_vector_type(8))) short bf16x8;
typedef __attribute__((ext_vector_type(4))) float f32x4;

// round-to-nearest-even f32 -> bf16 bits
__device__ __forceinline__ unsigned short f2bf(float f) {
  union { float f; unsigned int u; } v;
  v.f = f;
  const unsigned int r = v.u + 0x7fffu + ((v.u >> 16) & 1u);
  return (unsigned short)(r >> 16);
}

// ---------- kernel 1: fused softmax + shifted weighted sum -> bf16 z --------
// z[row][m] = sum_{s=0..127} softmax(pw)[s] * tok[row][s][(m+s)%D]
// Block = (m-chunk of 512, row). Thread t: output group og = Gb + (t&127);
// s-half h = t>>7 covers s-quads q = 16h..16h+15. Halves combined via LDS.
__global__ __launch_bounds__(256) void zshift_k(const float* __restrict__ tok,
                                                const float* __restrict__ pw,
                                                unsigned short* __restrict__ zb) {
  const int t = threadIdx.x;
  const int mc = blockIdx.x;   // 0..7
  const int row = blockIdx.y;  // 0..63

  __shared__ float wsh[BS];
  __shared__ float red[4];
  __shared__ float4 xsh[128];
  {
    const float v = (t < BS) ? pw[t] : -1e30f;
    float m = v;
#pragma unroll
    for (int o = 32; o > 0; o >>= 1) m = fmaxf(m, __shfl_xor(m, o));
    if ((t & 63) == 0) red[t >> 6] = m;
    __syncthreads();
    m = fmaxf(fmaxf(red[0], red[1]), fmaxf(red[2], red[3]));
    const float e = (t < BS) ? expf(v - m) : 0.f;
    float s = e;
#pragma unroll
    for (int o = 32; o > 0; o >>= 1) s += __shfl_xor(s, o);
    __syncthreads();
    if ((t & 63) == 0) red[t >> 6] = s;
    __syncthreads();
    s = red[0] + red[1] + red[2] + red[3];
    if (t < BS) wsh[t] = e / s;
    __syncthreads();
  }

  const int g = t & 127;        // local output group
  const int h = t >> 7;         // s-half (wave-uniform)
  const int og = (mc << 7) + g; // global output group (4 floats)
  const float4* tr = (const float4*)(tok + (size_t)row * (BS * D));

  float4 acc = make_float4(0.f, 0.f, 0.f, 0.f);
#pragma unroll
  for (int qq = 0; qq < 16; ++qq) {
    const int q = (h << 4) + qq;   // s-quad, s = 4q + r
    const float w0 = wsh[4 * q + 0], w1 = wsh[4 * q + 1];
    const float w2 = wsh[4 * q + 2], w3 = wsh[4 * q + 3];
    const int G = (og + q) & 1023;
    const int G1 = (G + 1) & 1023;
    const size_t r0 = (size_t)(4 * q + 0) << 10;
    const size_t r1 = (size_t)(4 * q + 1) << 10;
    const size_t r2 = (size_t)(4 * q + 2) << 10;
    const size_t r3 = (size_t)(4 * q + 3) << 10;
    const float4 a0 = tr[r0 + G];
    const float4 a1 = tr[r1 + G], b1 = tr[r1 + G1];
    const float4 a2 = tr[r2 + G], b2 = tr[r2 + G1];
    const float4 a3 = tr[r3 + G], b3 = tr[r3 + G1];
    acc.x += w0 * a0.x; acc.y += w0 * a0.y;
    acc.z += w0 * a0.z; acc.w += w0 * a0.w;
    acc.x += w1 * a1.y; acc.y += w1 * a1.z;
    acc.z += w1 * a1.w; acc.w += w1 * b1.x;
    acc.x += w2 * a2.z; acc.y += w2 * a2.w;
    acc.z += w2 * b2.x; acc.w += w2 * b2.y;
    acc.x += w3 * a3.w; acc.y += w3 * b3.x;
    acc.z += w3 * b3.y; acc.w += w3 * b3.z;
  }
  if (h) xsh[g] = acc;
  __syncthreads();
  if (!h) {
    const float4 o = xsh[g];
    ushort4 u;
    u.x = f2bf(acc.x + o.x);
    u.y = f2bf(acc.y + o.y);
    u.z = f2bf(acc.z + o.z);
    u.w = f2bf(acc.w + o.w);
    *(ushort4*)(zb + (size_t)row * D + ((size_t)og << 2)) = u;
  }
}

// ---------- kernel 2: circulant matmul via bf16 MFMA ------------------------
// braw[jc][row][d] = sum_{m in chunk} z[row][m] * base[(m-d)%D]
// C^T formulation: M=d (A = circulant), N=row (B = z), K=m.
__global__ __launch_bounds__(256) void corr_k(const unsigned short* __restrict__ zb,
                                              const float* __restrict__ base,
                                              float* __restrict__ braw) {
  __shared__ __align__(16) unsigned short zsh[16 * ZSTR];  // 16 rows x 512 bf16
  __shared__ __align__(16) unsigned short psh[8 * PSTR];   // 8 parity copies
  const int t = threadIdx.x;
  const int jc = blockIdx.x;   // 0..7   K-chunk
  const int dg = blockIdx.y;   // 0..63  64 d's per block
  const int rt = blockIdx.z;   // 0..3   16 rows per block
  const int jb = jc << 9;
  const int d0b = dg << 6;

  // stage zsh: 16 rows x 512 bf16; thread (rr = t>>4) writes 32 u16 at (t&15)*32
  {
    const int rr = t >> 4;
    const int c0 = (t & 15) << 5;
    const uint4* src =
        (const uint4*)(zb + (size_t)(rt * 16 + rr) * D + jb + c0);
    uint4* dst = (uint4*)(zsh + rr * ZSTR + c0);
    dst[0] = src[0];
    dst[1] = src[1];
    dst[2] = src[2];
    dst[3] = src[3];
  }
  // stage parity copies: psh[r][x] = bf16(base[(jb - d0b - 64 + r + x) & DM])
  {
    const int c0 = jb - d0b - 64 + 2 * D;  // keep positive
    for (int idx = t; idx < 8 * PSTR; idx += 256) {
      const int r = idx / PSTR;
      const int x = idx - r * PSTR;
      psh[idx] = f2bf(base[(c0 + r + x) & DM]);
    }
  }
  __syncthreads();

  const int lane = t & 63;
  const int w = t >> 6;        // wave id: d-subtile
  const int dd = lane & 15;    // A: m-index (d offset); B: n-index (row offset)
  const int q = lane >> 4;     // k = 8q + j
  // A fragment window start: a0 = 64 + 8q - 16w - dd (>=1), +32 per ks
  const int a0 = 64 + (q << 3) - (w << 4) - dd;
  const int pr = a0 & 7;
  const int px = a0 - pr;      // multiple of 8 -> 16B aligned
  const unsigned short* pA = psh + pr * PSTR + px;
  const unsigned short* pB = zsh + dd * ZSTR + (q << 3);

  f32x4 acc = {0.f, 0.f, 0.f, 0.f};
#pragma unroll
  for (int ks = 0; ks < 16; ++ks) {
    const bf16x8 af = *(const bf16x8*)(pA + (ks << 5));
    const bf16x8 bf = *(const bf16x8*)(pB + (ks << 5));
    acc = __builtin_amdgcn_mfma_f32_16x16x32_bf16(af, bf, acc, 0, 0, 0);
  }
  // D: col(n)=lane&15 -> output row; row(m)=quad*4+reg -> d index
  const int row = rt * 16 + dd;
  const int d = d0b + (w << 4) + (q << 2);
  float4 o = make_float4(acc[0], acc[1], acc[2], acc[3]);
  *(float4*)(braw + (size_t)(jc * NROW + row) * D + d) = o;
}

// ---------- kernel 3: sum K-chunk partials + L2 normalize -------------------
__global__ __launch_bounds__(1024) void norm_k(const float* __restrict__ braw,
                                               float* __restrict__ out) {
  const int t = threadIdx.x;
  const int row = blockIdx.x;
  const float4* b4 = (const float4*)braw;
  float4 s = make_float4(0.f, 0.f, 0.f, 0.f);
#pragma unroll
  for (int p = 0; p < JC; ++p) {
    const float4 v = b4[(size_t)(p * NROW + row) * (D / 4) + t];
    s.x += v.x; s.y += v.y; s.z += v.z; s.w += v.w;
  }
  float ssq = s.x * s.x + s.y * s.y + s.z * s.z + s.w * s.w;
#pragma unroll
  for (int o = 32; o > 0; o >>= 1) ssq += __shfl_xor(ssq, o);
  __shared__ float red[16];
  if ((t & 63) == 0) red[t >> 6] = ssq;
  __syncthreads();
  float tot = 0.f;
#pragma unroll
  for (int i = 0; i < 16; ++i) tot += red[i];
  const float sc = rsqrtf(fmaxf(tot, 1e-8f));
  float4 o;
  o.x = s.x * sc; o.y = s.y * sc; o.z = s.z * sc; o.w = s.w * sc;
  ((float4*)out)[(size_t)row * (D / 4) + t] = o;
}

extern "C" void kernel_launch(void* const* d_in, const int* in_sizes, int n_in,
                              void* d_out, int out_size, void* d_ws, size_t ws_size,
                              hipStream_t stream) {
  (void)in_sizes; (void)n_in; (void)out_size; (void)ws_size;
  const float* tok = (const float*)d_in[0];   // [4,2048,4096] f32
  const float* base = (const float*)d_in[1];  // [4096] f32
  const float* pw = (const float*)d_in[2];    // [128] f32
  float* out = (float*)d_out;                 // [64,4096] f32

  unsigned short* zb = (unsigned short*)d_ws;          // 64*4096 bf16 (512 KB)
  float* braw = (float*)(zb + (size_t)NROW * D);       // JC*64*4096 f32 (8 MB)

  zshift_k<<<dim3(8, NROW), 256, 0, stream>>>(tok, pw, zb);
  corr_k<<<dim3(JC, 64, 4), 256, 0, stream>>>(zb, base, braw);
  norm_k<<<NROW, 1024, 0, stream>>>(braw, out);
}